// Round 1
// baseline (180.576 us; speedup 1.0000x reference)
//
#include <hip/hip_runtime.h>
#include <math.h>

// Problem constants (fixed by setup_inputs): B=4, T=4096, D=1024, N=512
#define D_DIM 1024
#define N_BUF 512
#define ROWS 16384              // B*T
#define TOTAL 16777216          // B*T*D floats
#define TOTAL4 (TOTAL / 4)      // 4194304 float4
#define K1_BLOCKS 1024
#define K1_THREADS 256
#define K1_STRIDE (K1_BLOCKS * K1_THREADS)      // 262144
#define K1_ITERS (TOTAL4 / K1_STRIDE)           // 16
#define SUM_STRIDE 16           // pad each column-sum to its own 64B line (atomic contention)
#define SUMS_FLOATS (D_DIM * SUM_STRIDE)        // 16384
#define SIMS_OFF SUMS_FLOATS                    // ws[16384 .. 16896): sims[512]
#define GATE_OFF (SIMS_OFF + N_BUF)             // ws[16896]: gate scalar

// gelu(x) = 0.5x(1+tanh(u)), u = sqrt(2/pi)(x + 0.044715 x^3)
// tanh(u) = 1 - 2/(e^{2u}+1)  =>  y = x * (1 - 1/(e^{2u}+1))
// Saturates correctly: e->0 gives y=0 (x<<0), e->inf gives y=x (x>>0). No inf/inf.
__device__ __forceinline__ float gelu_f(float x) {
    float u = 0.7978845608028654f * (x + 0.044715f * x * x * x);
    float e = __expf(2.0f * u);
    return x * (1.0f - 1.0f / (e + 1.0f));
}

// ---- K0: zero the padded column-sum region (ws is poisoned 0xAA each call) ----
__global__ void k_zero(float* __restrict__ p, int n) {
    int i = blockIdx.x * blockDim.x + threadIdx.x;
    if (i < n) p[i] = 0.0f;
}

// ---- K1: y = gelu(x) -> out, plus per-column sum accumulation ----
// Thread t of any block always touches columns 4t..4t+3 (stride 262144 float4
// == 0 mod 256 float4-columns), so it keeps 4 register accumulators and does
// 4 global atomicAdds at the end (padded: one cache line per column).
__global__ __launch_bounds__(K1_THREADS) void k_gelu_sum(
        const float* __restrict__ x, float* __restrict__ out,
        float* __restrict__ sums) {
    const int t = threadIdx.x;
    const int gtid = blockIdx.x * K1_THREADS + t;
    const float4* __restrict__ x4 = (const float4*)x;
    float4* __restrict__ o4 = (float4*)out;

    float a0 = 0.f, a1 = 0.f, a2 = 0.f, a3 = 0.f;
    int idx = gtid;
#pragma unroll 4
    for (int k = 0; k < K1_ITERS; ++k, idx += K1_STRIDE) {
        float4 v = x4[idx];
        float y0 = gelu_f(v.x), y1 = gelu_f(v.y), y2 = gelu_f(v.z), y3 = gelu_f(v.w);
        o4[idx] = make_float4(y0, y1, y2, y3);
        a0 += y0; a1 += y1; a2 += y2; a3 += y3;
    }
    const int c = 4 * t;
    atomicAdd(&sums[(c + 0) * SUM_STRIDE], a0);
    atomicAdd(&sums[(c + 1) * SUM_STRIDE], a1);
    atomicAdd(&sums[(c + 2) * SUM_STRIDE], a2);
    atomicAdd(&sums[(c + 3) * SUM_STRIDE], a3);
}

__device__ __forceinline__ float block_reduce_sum256(float v, float* red) {
    const int lane = threadIdx.x & 63, w = threadIdx.x >> 6;
#pragma unroll
    for (int o = 32; o > 0; o >>= 1) v += __shfl_down(v, o);
    if (lane == 0) red[w] = v;
    __syncthreads();
    float r = red[0] + red[1] + red[2] + red[3];
    __syncthreads();   // make red reusable by a subsequent call
    return r;
}

// ---- K2a: sims[r] for each buffer row (one block per row, avoids a serial
//           2MB read on a single CU) ----
// sim = (buf_r . m) / (max(||m||,eps) * max(||buf_r||,eps)); masked -> -1
__global__ __launch_bounds__(256) void k_sims(
        const float* __restrict__ sums, const float* __restrict__ buf,
        const unsigned char* __restrict__ mask, float* __restrict__ sims_out) {
    __shared__ float red[4];
    const int r = blockIdx.x;
    float dot = 0.f, nm2 = 0.f, nb2 = 0.f;
    for (int c = threadIdx.x; c < D_DIM; c += 256) {
        float m = sums[c * SUM_STRIDE] * (1.0f / (float)ROWS);
        float b = buf[r * D_DIM + c];
        dot += b * m;
        nm2 += m * m;
        nb2 += b * b;
    }
    dot = block_reduce_sum256(dot, red);
    nm2 = block_reduce_sum256(nm2, red);
    nb2 = block_reduce_sum256(nb2, red);
    if (threadIdx.x == 0) {
        float s = dot / (fmaxf(sqrtf(nm2), 1e-12f) * fmaxf(sqrtf(nb2), 1e-12f));
        sims_out[r] = mask[r] ? s : -1.0f;
    }
}

// ---- K2b: argmax over sims, sim_g, and the final gate scalar ----
__global__ __launch_bounds__(256) void k_gate(
        const float* __restrict__ sums, const float* __restrict__ sims,
        const float* __restrict__ facil_l, const float* __restrict__ gmean,
        const float* __restrict__ facil_g, const float* __restrict__ lkl,
        const float* __restrict__ lkg, float* __restrict__ gate_out) {
    __shared__ float red[4];
    __shared__ float s_best;
    __shared__ int s_bi;
    const int t = threadIdx.x, lane = t & 63, w = t >> 6;

    float nm2 = 0.f, g = 0.f;
    for (int c = t; c < D_DIM; c += 256) {
        float m = sums[c * SUM_STRIDE] * (1.0f / (float)ROWS);
        nm2 += m * m;
        g += m * gmean[c];
    }
    nm2 = block_reduce_sum256(nm2, red);
    g = block_reduce_sum256(g, red);

    if (w == 0) {  // argmax (first-max semantics, like jnp.argmax)
        float best = -2.0f; int bi = 0;
        for (int r = lane; r < N_BUF; r += 64) {
            float s = sims[r];
            if (s > best) { best = s; bi = r; }
        }
#pragma unroll
        for (int o = 32; o > 0; o >>= 1) {
            float ob = __shfl_down(best, o);
            int oi = __shfl_down(bi, o);
            if (ob > best || (ob == best && oi < bi)) { best = ob; bi = oi; }
        }
        if (lane == 0) { s_best = best; s_bi = bi; }
    }
    __syncthreads();

    if (t == 0) {
        float sim_l = fminf(fmaxf(s_best, 0.0f), 1.0f);
        float sim_g = fminf(fmaxf(g / fmaxf(sqrtf(nm2), 1e-12f), 0.0f), 1.0f);
        bool fire = sim_l > 0.85f;
        float fl = facil_l[s_bi] * (fire ? 2.0f : 1.0f);
        float fg = fire ? fminf(facil_g[0] * 1.5f, 16.0f) : facil_g[0];
        float kl = fminf(fmaxf(expf(lkl[0]), 0.01f), 4.0f);
        float kg = fminf(fmaxf(expf(lkg[0]), 0.01f), 4.0f);
        gate_out[0] = fminf(1.0f + kl * (fl - 1.0f) * sim_l + kg * (fg - 1.0f) * sim_g, 8.0f);
    }
}

// ---- K3: out *= gate; early-exit when gate == 1.0 (the expected case:
//          facil_l==1, facil_g==1, fire=false -> gate is exactly 1.0f) ----
__global__ __launch_bounds__(256) void k_scale(
        float* __restrict__ out, const float* __restrict__ gate) {
    const float gv = gate[0];
    if (gv == 1.0f) return;
    const int gtid = blockIdx.x * K1_THREADS + threadIdx.x;
    float4* __restrict__ o4 = (float4*)out;
    int idx = gtid;
#pragma unroll 4
    for (int k = 0; k < K1_ITERS; ++k, idx += K1_STRIDE) {
        float4 v = o4[idx];
        v.x *= gv; v.y *= gv; v.z *= gv; v.w *= gv;
        o4[idx] = v;
    }
}

extern "C" void kernel_launch(void* const* d_in, const int* in_sizes, int n_in,
                              void* d_out, int out_size, void* d_ws, size_t ws_size,
                              hipStream_t stream) {
    const float* x        = (const float*)d_in[0];
    const float* lkl      = (const float*)d_in[1];
    const float* lkg      = (const float*)d_in[2];
    const float* buf      = (const float*)d_in[3];
    const float* facil_l  = (const float*)d_in[4];
    const float* gmean    = (const float*)d_in[5];
    const float* facil_g  = (const float*)d_in[6];
    const unsigned char* mask = (const unsigned char*)d_in[7];
    float* out = (float*)d_out;
    float* ws  = (float*)d_ws;

    // ws layout: [0, 16384) padded column sums; [16384, 16896) sims; [16896] gate
    k_zero<<<dim3(SUMS_FLOATS / 256), dim3(256), 0, stream>>>(ws, SUMS_FLOATS);
    k_gelu_sum<<<dim3(K1_BLOCKS), dim3(K1_THREADS), 0, stream>>>(x, out, ws);
    k_sims<<<dim3(N_BUF), dim3(256), 0, stream>>>(ws, buf, mask, ws + SIMS_OFF);
    k_gate<<<dim3(1), dim3(256), 0, stream>>>(ws, ws + SIMS_OFF, facil_l, gmean,
                                              facil_g, lkl, lkg, ws + GATE_OFF);
    k_scale<<<dim3(K1_BLOCKS), dim3(K1_THREADS), 0, stream>>>(out, ws + GATE_OFF);
}

// Round 3
// 153.596 us; speedup vs baseline: 1.1757x; 1.1757x over previous
//
#include <hip/hip_runtime.h>
#include <math.h>

// Problem constants (fixed by setup_inputs): B=4, T=4096, D=1024, N=512
#define D_DIM 1024
#define N_BUF 512
#define ROWS 16384                // B*T
#define TOTAL4 4194304            // B*T*D / 4 float4s
#define NB1 1024                  // K1 grid
#define NT1 256
#define K1_STRIDE (NB1 * NT1)     // 262144 float4
#define K1_ITERS (TOTAL4 / K1_STRIDE)   // 16

// ws layout (float offsets)
#define PART_FLOATS (NB1 * D_DIM)        // 1,048,576 floats = 4 MB
#define M_OFF PART_FLOATS                // m[1024]
#define SIMS_OFF (M_OFF + D_DIM)         // sims[512]
#define GATE_OFF (SIMS_OFF + N_BUF)      // gate scalar

// clang-native 16B vector (HIP's float4 is a class; the nontemporal builtin
// and cleanest codegen want an ext_vector_type)
typedef float vfloat4 __attribute__((ext_vector_type(4)));

// gelu(x) = 0.5x(1+tanh(u)), u = sqrt(2/pi)(x + 0.044715 x^3)
// tanh(u) = 1 - 2/(e^{2u}+1)  =>  y = x * (1 - rcp(e^{2u}+1))
// x<<0: e->0, rcp(1)=1 -> y=0.  x>>0: e->inf, rcp->0 -> y=x.  No inf/inf.
__device__ __forceinline__ float gelu_f(float x) {
    float u = 0.7978845608028654f * (x + 0.044715f * x * x * x);
    float e = __expf(2.0f * u);
    return x * (1.0f - __builtin_amdgcn_rcpf(e + 1.0f));
}

// ---- K1: y = gelu(x) -> out (nontemporal), per-block column partial sums ----
// Grid stride 262144 float4 == 0 mod 256, so thread t always touches
// float4-column t (columns 4t..4t+3): 4 register accumulators, then ONE
// coalesced 16B store per thread into partials[block][1024]. No atomics.
__global__ __launch_bounds__(NT1) void k_gelu_part(
        const float* __restrict__ x, float* __restrict__ out,
        float* __restrict__ partials) {
    const int t = threadIdx.x;
    const vfloat4* __restrict__ x4 = (const vfloat4*)x;
    vfloat4* __restrict__ o4 = (vfloat4*)out;

    vfloat4 acc = (vfloat4)(0.0f);
    int idx = blockIdx.x * NT1 + t;
#pragma unroll 8
    for (int k = 0; k < K1_ITERS; ++k, idx += K1_STRIDE) {
        vfloat4 v = x4[idx];
        vfloat4 y;
        y.x = gelu_f(v.x); y.y = gelu_f(v.y); y.z = gelu_f(v.z); y.w = gelu_f(v.w);
        __builtin_nontemporal_store(y, &o4[idx]);
        acc += y;
    }
    ((vfloat4*)partials)[blockIdx.x * NT1 + t] = acc;
}

// ---- K2: reduce partials over blocks -> m[1024] (grid 16 x 256) ----
// Block g handles columns [g*64, g*64+64); the 4 waves each sum a quarter
// of the 1024 blocks, LDS-combined at the end.
__global__ __launch_bounds__(256) void k_reduce(
        const float* __restrict__ partials, float* __restrict__ m) {
    __shared__ float red[4][64];
    const int t = threadIdx.x, sub = t >> 6, lane = t & 63;
    const int col = blockIdx.x * 64 + lane;
    const int b0 = sub * (NB1 / 4);
    float s = 0.f;
#pragma unroll 8
    for (int i = 0; i < NB1 / 4; ++i) s += partials[(b0 + i) * D_DIM + col];
    red[sub][lane] = s;
    __syncthreads();
    if (sub == 0) {
        float tot = red[0][lane] + red[1][lane] + red[2][lane] + red[3][lane];
        m[col] = tot * (1.0f / (float)ROWS);
    }
}

__device__ __forceinline__ float block_reduce_sum256(float v, float* red) {
    const int lane = threadIdx.x & 63, w = threadIdx.x >> 6;
#pragma unroll
    for (int o = 32; o > 0; o >>= 1) v += __shfl_down(v, o);
    if (lane == 0) red[w] = v;
    __syncthreads();
    float r = red[0] + red[1] + red[2] + red[3];
    __syncthreads();
    return r;
}

// ---- K3: sims[r] per buffer row (one block per row) ----
__global__ __launch_bounds__(256) void k_sims(
        const float* __restrict__ m, const float* __restrict__ buf,
        const unsigned char* __restrict__ mask, float* __restrict__ sims_out) {
    __shared__ float red[4];
    const int r = blockIdx.x;
    float dot = 0.f, nm2 = 0.f, nb2 = 0.f;
    for (int c = threadIdx.x; c < D_DIM; c += 256) {
        float mv = m[c];
        float b = buf[r * D_DIM + c];
        dot += b * mv;
        nm2 += mv * mv;
        nb2 += b * b;
    }
    dot = block_reduce_sum256(dot, red);
    nm2 = block_reduce_sum256(nm2, red);
    nb2 = block_reduce_sum256(nb2, red);
    if (threadIdx.x == 0) {
        float s = dot / (fmaxf(sqrtf(nm2), 1e-12f) * fmaxf(sqrtf(nb2), 1e-12f));
        sims_out[r] = mask[r] ? s : -1.0f;
    }
}

// ---- K4: argmax over sims, sim_g, final gate scalar (1 block) ----
__global__ __launch_bounds__(256) void k_gate(
        const float* __restrict__ m, const float* __restrict__ sims,
        const float* __restrict__ facil_l, const float* __restrict__ gmean,
        const float* __restrict__ facil_g, const float* __restrict__ lkl,
        const float* __restrict__ lkg, float* __restrict__ gate_out) {
    __shared__ float red[4];
    __shared__ float s_best;
    __shared__ int s_bi;
    const int t = threadIdx.x, lane = t & 63, w = t >> 6;

    float nm2 = 0.f, g = 0.f;
    for (int c = t; c < D_DIM; c += 256) {
        float mv = m[c];
        nm2 += mv * mv;
        g += mv * gmean[c];
    }
    nm2 = block_reduce_sum256(nm2, red);
    g = block_reduce_sum256(g, red);

    if (w == 0) {  // first-max argmax, jnp semantics
        float best = -2.0f; int bi = 0;
        for (int r = lane; r < N_BUF; r += 64) {
            float s = sims[r];
            if (s > best) { best = s; bi = r; }
        }
#pragma unroll
        for (int o = 32; o > 0; o >>= 1) {
            float ob = __shfl_down(best, o);
            int oi = __shfl_down(bi, o);
            if (ob > best || (ob == best && oi < bi)) { best = ob; bi = oi; }
        }
        if (lane == 0) { s_best = best; s_bi = bi; }
    }
    __syncthreads();

    if (t == 0) {
        float sim_l = fminf(fmaxf(s_best, 0.0f), 1.0f);
        float sim_g = fminf(fmaxf(g / fmaxf(sqrtf(nm2), 1e-12f), 0.0f), 1.0f);
        bool fire = sim_l > 0.85f;
        float fl = facil_l[s_bi] * (fire ? 2.0f : 1.0f);
        float fg = fire ? fminf(facil_g[0] * 1.5f, 16.0f) : facil_g[0];
        float kl = fminf(fmaxf(expf(lkl[0]), 0.01f), 4.0f);
        float kg = fminf(fmaxf(expf(lkg[0]), 0.01f), 4.0f);
        gate_out[0] = fminf(1.0f + kl * (fl - 1.0f) * sim_l + kg * (fg - 1.0f) * sim_g, 8.0f);
    }
}

// ---- K5: out *= gate; early-exit when gate == 1.0 (expected case) ----
__global__ __launch_bounds__(NT1) void k_scale(
        float* __restrict__ out, const float* __restrict__ gate) {
    const float gv = gate[0];
    if (gv == 1.0f) return;
    vfloat4* __restrict__ o4 = (vfloat4*)out;
    int idx = blockIdx.x * NT1 + threadIdx.x;
#pragma unroll 4
    for (int k = 0; k < K1_ITERS; ++k, idx += K1_STRIDE) {
        vfloat4 v = o4[idx];
        v *= gv;
        o4[idx] = v;
    }
}

extern "C" void kernel_launch(void* const* d_in, const int* in_sizes, int n_in,
                              void* d_out, int out_size, void* d_ws, size_t ws_size,
                              hipStream_t stream) {
    const float* x        = (const float*)d_in[0];
    const float* lkl      = (const float*)d_in[1];
    const float* lkg      = (const float*)d_in[2];
    const float* buf      = (const float*)d_in[3];
    const float* facil_l  = (const float*)d_in[4];
    const float* gmean    = (const float*)d_in[5];
    const float* facil_g  = (const float*)d_in[6];
    const unsigned char* mask = (const unsigned char*)d_in[7];
    float* out = (float*)d_out;
    float* ws  = (float*)d_ws;

    float* partials = ws;
    float* m        = ws + M_OFF;
    float* sims     = ws + SIMS_OFF;
    float* gate     = ws + GATE_OFF;

    k_gelu_part<<<dim3(NB1), dim3(NT1), 0, stream>>>(x, out, partials);
    k_reduce<<<dim3(16), dim3(256), 0, stream>>>(partials, m);
    k_sims<<<dim3(N_BUF), dim3(256), 0, stream>>>(m, buf, mask, sims);
    k_gate<<<dim3(1), dim3(256), 0, stream>>>(m, sims, facil_l, gmean,
                                              facil_g, lkl, lkg, gate);
    k_scale<<<dim3(NB1), dim3(NT1), 0, stream>>>(out, gate);
}